// Round 4
// baseline (447.444 us; speedup 1.0000x reference)
//
#include <hip/hip_runtime.h>
#include <hip/hip_bf16.h>

#define BATCH 128
#define LQ    512
#define LK    512
#define DH    64
#define TQ    16
#define SSTR  520   // bf16 attn overlay stride (verified bank-minimal b64 w / b128 r)
#define VROW  72    // prologue transpose tile stride (verified)

// workspace layout (shorts): Kbf[128][512][64] | Vt[128][64][512] | Qbf[128][512][64]
// then (dwords) KMb[128*512*16] | QMb[128*512*16]  (consumer-lane-order bitmasks)
#define WS_K 0
#define WS_V 4194304
#define WS_Q 8388608
#define WS_MB_SHORT 12582912          // short offset where dword masks begin
#define WS_BYTES_QKV 25165824ull      // K/V/Q only (raw-mask mid path)
#define WS_BYTES_FULL 33554432ull     // + 2 x 4 MB packed masks

typedef float    float4v __attribute__((ext_vector_type(4)));
typedef short    short8v __attribute__((ext_vector_type(8)));
typedef short    short4v __attribute__((ext_vector_type(4)));
typedef int      int4v   __attribute__((ext_vector_type(4)));
typedef _Float16 half4v  __attribute__((ext_vector_type(4)));

__device__ __forceinline__ short bf16r(float f) {
  union { float f; unsigned u; } x; x.f = f;
  unsigned r = x.u + 0x7FFFu + ((x.u >> 16) & 1u);
  return (short)(r >> 16);
}

// ========= prologue: K/Q->bf16, V->Vt bf16, masks->lane-order bits ==========
// grid 3328 (full) or 1280 (no mask packing):
//   [0,1024)      V transpose tiles
//   [1024,1152)   K convert     [1152,1280) Q convert
//   [1280,2304)   KM bit-pack   [2304,3328) QM bit-pack
__global__ __launch_bounds__(256)
void prep_kernel(const float* __restrict__ Q, const float* __restrict__ K,
                 const float* __restrict__ V, const int* __restrict__ KM,
                 const int* __restrict__ QM, short* __restrict__ ws)
{
  const int bid = blockIdx.x, tid = threadIdx.x;
  if (bid < 1024) {
    // ---- V transpose: one 64k x 64d tile -> Vt[b][d][k] --------------------
    __shared__ short T[64 * VROW];
    const int b  = bid >> 3;
    const int k0 = (bid & 7) * 64;
    const int bR = tid >> 4;
    const int bC = tid & 15;
    const float* vp = V + ((size_t)(b * LK + k0 + bR * 4)) * DH + bC * 4;
    float4v r0 = *(const float4v*)(vp);
    float4v r1 = *(const float4v*)(vp + DH);
    float4v r2 = *(const float4v*)(vp + 2 * DH);
    float4v r3 = *(const float4v*)(vp + 3 * DH);
#pragma unroll
    for (int e = 0; e < 4; ++e) {
      int d  = bC * 4 + e;
      int gp = bR ^ (d & 15);
      short4v s4;
      s4[0] = bf16r(r0[e]); s4[1] = bf16r(r1[e]);
      s4[2] = bf16r(r2[e]); s4[3] = bf16r(r3[e]);
      *(short4v*)&T[d * VROW + gp * 4] = s4;
    }
    __syncthreads();
    const int d  = tid >> 2;
    const int g0 = (tid & 3) * 4;
    short v16[16];
#pragma unroll
    for (int s2 = 0; s2 < 4; ++s2) {
      int g = g0 + s2;
      short4v t4 = *(const short4v*)&T[d * VROW + ((g ^ (d & 15)) * 4)];
      v16[s2 * 4 + 0] = t4[0]; v16[s2 * 4 + 1] = t4[1];
      v16[s2 * 4 + 2] = t4[2]; v16[s2 * 4 + 3] = t4[3];
    }
    short* dst = ws + WS_V + ((size_t)(b * DH + d)) * LK + k0 + g0 * 4;
    *(short8v*)(dst)     = *(short8v*)&v16[0];
    *(short8v*)(dst + 8) = *(short8v*)&v16[8];
  } else if (bid < 1280) {
    // ---- K / Q convert ----------------------------------------------------
    const bool isK = (bid < 1152);
    const size_t base = (size_t)((isK ? bid - 1024 : bid - 1152)) * 32768;
    const float* src = (isK ? K : Q) + base;
    short* dst = ws + (isK ? WS_K : WS_Q) + base;
#pragma unroll 4
    for (int u = 0; u < 32; ++u) {
      float4v f = *(const float4v*)(src + u * 1024 + tid * 4);
      short4v s4;
      s4[0] = bf16r(f[0]); s4[1] = bf16r(f[1]);
      s4[2] = bf16r(f[2]); s4[3] = bf16r(f[3]);
      *(short4v*)(dst + u * 1024 + tid * 4) = s4;
    }
  } else {
    // ---- mask bit-pack in consumer lane order -----------------------------
    // block: 64 q rows of one batch; thread: (q_local=tid>>2, wv=tid&3),
    // produces 4 dwords (quad 0..3); bit t*4+e <-> key wv*128+t*16+quad*4+e
    const bool isKM = (bid < 2304);
    const int  mi   = bid - (isKM ? 1280 : 2304);
    const int  b    = mi >> 3;
    const int  q0   = (mi & 7) * 64;
    const int  ql   = tid >> 2;
    const int  wv   = tid & 3;
    const int* src  = (isKM ? KM : QM) +
                      ((size_t)(b * LQ + q0 + ql)) * LK + wv * 128;
    unsigned bits[4] = {0u, 0u, 0u, 0u};
#pragma unroll
    for (int t = 0; t < 8; ++t) {
#pragma unroll
      for (int quad = 0; quad < 4; ++quad) {
        int4v m4 = *(const int4v*)(src + t * 16 + quad * 4);
#pragma unroll
        for (int e = 0; e < 4; ++e)
          bits[quad] |= (unsigned)(m4[e] != 0) << (t * 4 + e);
      }
    }
    unsigned* mb = (unsigned*)(ws + WS_MB_SHORT) + (isKM ? 0u : 1048576u);
    // dword index (qg*16 + wv*4 + quad); int4 store covers quad 0..3
    *(int4v*)(mb + ((size_t)(b * LQ + q0 + ql)) * 16 + wv * 4) =
        *(const int4v*)bits;
  }
}

// ============== main (packed masks): swapped-QK^T, reg softmax ==============
__global__ __launch_bounds__(256, 4)
void sdpa_main_packed(const short* __restrict__ Kbf, const short* __restrict__ Vt,
                      const short* __restrict__ Qbf,
                      const unsigned* __restrict__ KMB,
                      const unsigned* __restrict__ QMB,
                      float* __restrict__ OUT, float* __restrict__ ATT)
{
  __shared__ short sc[TQ * SSTR];    // bf16 attn (only LDS tile)
  __shared__ float cmb[2][64];       // cross-wave max / sum partials

  const int bid  = blockIdx.x;
  const int wg   = ((bid & 7) << 9) | (bid >> 3);   // XCD-contiguous, bijective
  const int b    = wg >> 5;
  const int q0   = (wg & 31) * TQ;
  const int tid  = threadIdx.x;
  const int lane = tid & 63;
  const int wv   = tid >> 6;
  const int lm   = lane & 15;
  const int quad = lane >> 4;

  const size_t qg    = (size_t)(b * LQ + q0 + lm);
  const size_t mbase = qg * LK + wv * 128 + quad * 4;

  // one dword per mask per lane -- the whole mask chain
  const unsigned kb  = KMB[qg * 16 + wv * 4 + quad];
  const unsigned qmb = QMB[qg * 16 + wv * 4 + quad];

  // Q B-fragments: two 16B bf16 loads (prepped)
  const short* qp = Qbf + qg * DH + quad * 8;
  const short8v qb0 = *(const short8v*)(qp);
  const short8v qb1 = *(const short8v*)(qp + 32);

  // ---------------- phase 1: S^T tiles, scores stay in registers ----------
  float s[32];
  const short* kp0 = Kbf + ((size_t)(b * LK + wv * 128 + lm)) * DH + quad * 8;
#pragma unroll
  for (int t = 0; t < 8; ++t) {
    const short* kp = kp0 + (size_t)t * 16 * DH;
    short8v ka0 = *(const short8v*)(kp);
    short8v ka1 = *(const short8v*)(kp + 32);
    float4v acc = {0.f, 0.f, 0.f, 0.f};
    acc = __builtin_amdgcn_mfma_f32_16x16x32_bf16(ka0, qb0, acc, 0, 0, 0);
    acc = __builtin_amdgcn_mfma_f32_16x16x32_bf16(ka1, qb1, acc, 0, 0, 0);
#pragma unroll
    for (int j = 0; j < 4; ++j) s[t * 4 + j] = acc[j];
  }

  // ---------------- phase 2: masks + softmax (in-register) ----------------
  float mx0 = -INFINITY, mx1 = -INFINITY, mx2 = -INFINITY, mx3 = -INFINITY;
#pragma unroll
  for (int t = 0; t < 8; ++t) {
#pragma unroll
    for (int e = 0; e < 4; ++e) {
      float v = ((kb >> (t * 4 + e)) & 1u) ? -INFINITY : s[t * 4 + e];
      s[t * 4 + e] = v;
      if (e == 0) mx0 = fmaxf(mx0, v);
      else if (e == 1) mx1 = fmaxf(mx1, v);
      else if (e == 2) mx2 = fmaxf(mx2, v);
      else mx3 = fmaxf(mx3, v);
    }
  }
  float mx = fmaxf(fmaxf(mx0, mx1), fmaxf(mx2, mx3));
  mx = fmaxf(mx, __shfl_xor(mx, 16, 64));
  mx = fmaxf(mx, __shfl_xor(mx, 32, 64));
  if (lane < 16) cmb[0][wv * 16 + lane] = mx;
  __syncthreads();
  mx = fmaxf(fmaxf(cmb[0][lm], cmb[0][16 + lm]),
             fmaxf(cmb[0][32 + lm], cmb[0][48 + lm]));

  float s0 = 0.f, s1 = 0.f, s2 = 0.f, s3 = 0.f;
#pragma unroll
  for (int t = 0; t < 8; ++t) {
    float p0 = __expf((s[t * 4 + 0] - mx) * 0.125f);
    float p1 = __expf((s[t * 4 + 1] - mx) * 0.125f);
    float p2 = __expf((s[t * 4 + 2] - mx) * 0.125f);
    float p3 = __expf((s[t * 4 + 3] - mx) * 0.125f);
    s[t * 4 + 0] = p0; s[t * 4 + 1] = p1;
    s[t * 4 + 2] = p2; s[t * 4 + 3] = p3;
    s0 += p0; s1 += p1; s2 += p2; s3 += p3;
  }
  float sum = (s0 + s1) + (s2 + s3);
  sum += __shfl_xor(sum, 16, 64);
  sum += __shfl_xor(sum, 32, 64);
  if (lane < 16) cmb[1][wv * 16 + lane] = sum;
  __syncthreads();
  sum = (cmb[1][lm] + cmb[1][16 + lm]) + (cmb[1][32 + lm] + cmb[1][48 + lm]);
  const float inv = __builtin_amdgcn_rcpf(sum);

  // ATT store (plain: L2 merges t/t+1 64B halves into full lines) + overlay
  float* arow = ATT + mbase;
  short* srow = &sc[lm * SSTR + wv * 128 + quad * 4];
#pragma unroll
  for (int t = 0; t < 8; ++t) {
    float4v a4;
#pragma unroll
    for (int e = 0; e < 4; ++e)
      a4[e] = ((qmb >> (t * 4 + e)) & 1u) ? 0.f : s[t * 4 + e] * inv;
    *(float4v*)(arow + t * 16) = a4;
    short4v ab;
    ab[0] = bf16r(a4[0]); ab[1] = bf16r(a4[1]);
    ab[2] = bf16r(a4[2]); ab[3] = bf16r(a4[3]);
    *(short4v*)(srow + t * 16) = ab;
  }
  __syncthreads();   // overlay complete before A-frag reads

  // ---------------- phase 3: O = A * Vt (barrier-free) --------------------
  float4v oa = {0.f, 0.f, 0.f, 0.f}, ob = {0.f, 0.f, 0.f, 0.f};
  const short* ap = &sc[lm * SSTR + quad * 8];
  const short* vp = Vt + ((size_t)(b * DH + wv * 16 + lm)) * LK + quad * 8;
#pragma unroll
  for (int c = 0; c < 16; c += 2) {
    short8v a0 = *(const short8v*)(ap + c * 32);
    short8v b0 = *(const short8v*)(vp + c * 32);
    short8v a1 = *(const short8v*)(ap + (c + 1) * 32);
    short8v b1 = *(const short8v*)(vp + (c + 1) * 32);
    oa = __builtin_amdgcn_mfma_f32_16x16x32_bf16(a0, b0, oa, 0, 0, 0);
    ob = __builtin_amdgcn_mfma_f32_16x16x32_bf16(a1, b1, ob, 0, 0, 0);
  }
  float4v oacc = oa + ob;
  float* obase = OUT + ((size_t)(b * LQ + q0 + quad * 4)) * DH + wv * 16 + lm;
  obase[0 * DH] = oacc[0];
  obase[1 * DH] = oacc[1];
  obase[2 * DH] = oacc[2];
  obase[3 * DH] = oacc[3];
}

// ============== main (raw masks): round-3 kernel, NT stores removed =========
__global__ __launch_bounds__(256, 4)
void sdpa_main_raw(const short* __restrict__ Kbf, const short* __restrict__ Vt,
                   const short* __restrict__ Qbf, const int* __restrict__ KM,
                   const int* __restrict__ QM, float* __restrict__ OUT,
                   float* __restrict__ ATT)
{
  __shared__ short sc[TQ * SSTR];
  __shared__ float cmb[2][64];
  const int bid  = blockIdx.x;
  const int wg   = ((bid & 7) << 9) | (bid >> 3);
  const int b    = wg >> 5;
  const int q0   = (wg & 31) * TQ;
  const int tid  = threadIdx.x;
  const int lane = tid & 63;
  const int wv   = tid >> 6;
  const int lm   = lane & 15;
  const int quad = lane >> 4;
  const size_t qg    = (size_t)(b * LQ + q0 + lm);
  const size_t mbase = qg * LK + wv * 128 + quad * 4;
  int4v kmv[8];
#pragma unroll
  for (int t = 0; t < 8; ++t)
    kmv[t] = __builtin_nontemporal_load((const int4v*)(KM + mbase + t * 16));
  const short* qp = Qbf + qg * DH + quad * 8;
  const short8v qb0 = *(const short8v*)(qp);
  const short8v qb1 = *(const short8v*)(qp + 32);
  float s[32];
  const short* kp0 = Kbf + ((size_t)(b * LK + wv * 128 + lm)) * DH + quad * 8;
#pragma unroll
  for (int t = 0; t < 8; ++t) {
    const short* kp = kp0 + (size_t)t * 16 * DH;
    short8v ka0 = *(const short8v*)(kp);
    short8v ka1 = *(const short8v*)(kp + 32);
    float4v acc = {0.f, 0.f, 0.f, 0.f};
    acc = __builtin_amdgcn_mfma_f32_16x16x32_bf16(ka0, qb0, acc, 0, 0, 0);
    acc = __builtin_amdgcn_mfma_f32_16x16x32_bf16(ka1, qb1, acc, 0, 0, 0);
#pragma unroll
    for (int j = 0; j < 4; ++j) s[t * 4 + j] = acc[j];
  }
  float mx = -INFINITY;
#pragma unroll
  for (int t = 0; t < 8; ++t)
#pragma unroll
    for (int e = 0; e < 4; ++e) {
      float v = kmv[t][e] ? -INFINITY : s[t * 4 + e];
      s[t * 4 + e] = v;
      mx = fmaxf(mx, v);
    }
  mx = fmaxf(mx, __shfl_xor(mx, 16, 64));
  mx = fmaxf(mx, __shfl_xor(mx, 32, 64));
  int4v qmv[8];
#pragma unroll
  for (int t = 0; t < 8; ++t)
    qmv[t] = __builtin_nontemporal_load((const int4v*)(QM + mbase + t * 16));
  if (lane < 16) cmb[0][wv * 16 + lane] = mx;
  __syncthreads();
  mx = fmaxf(fmaxf(cmb[0][lm], cmb[0][16 + lm]),
             fmaxf(cmb[0][32 + lm], cmb[0][48 + lm]));
  float sum = 0.f;
#pragma unroll
  for (int t = 0; t < 8; ++t)
#pragma unroll
    for (int e = 0; e < 4; ++e) {
      float p = __expf((s[t * 4 + e] - mx) * 0.125f);
      s[t * 4 + e] = p; sum += p;
    }
  sum += __shfl_xor(sum, 16, 64);
  sum += __shfl_xor(sum, 32, 64);
  if (lane < 16) cmb[1][wv * 16 + lane] = sum;
  __syncthreads();
  sum = (cmb[1][lm] + cmb[1][16 + lm]) + (cmb[1][32 + lm] + cmb[1][48 + lm]);
  const float inv = __builtin_amdgcn_rcpf(sum);
  float* arow = ATT + mbase;
  short* srow = &sc[lm * SSTR + wv * 128 + quad * 4];
#pragma unroll
  for (int t = 0; t < 8; ++t) {
    float4v a4;
#pragma unroll
    for (int e = 0; e < 4; ++e)
      a4[e] = qmv[t][e] ? 0.f : s[t * 4 + e] * inv;
    *(float4v*)(arow + t * 16) = a4;
    short4v ab;
    ab[0] = bf16r(a4[0]); ab[1] = bf16r(a4[1]);
    ab[2] = bf16r(a4[2]); ab[3] = bf16r(a4[3]);
    *(short4v*)(srow + t * 16) = ab;
  }
  __syncthreads();
  float4v oa = {0.f, 0.f, 0.f, 0.f}, ob = {0.f, 0.f, 0.f, 0.f};
  const short* ap = &sc[lm * SSTR + quad * 8];
  const short* vp = Vt + ((size_t)(b * DH + wv * 16 + lm)) * LK + quad * 8;
#pragma unroll
  for (int c = 0; c < 16; c += 2) {
    short8v a0 = *(const short8v*)(ap + c * 32);
    short8v b0 = *(const short8v*)(vp + c * 32);
    short8v a1 = *(const short8v*)(ap + (c + 1) * 32);
    short8v b1 = *(const short8v*)(vp + (c + 1) * 32);
    oa = __builtin_amdgcn_mfma_f32_16x16x32_bf16(a0, b0, oa, 0, 0, 0);
    ob = __builtin_amdgcn_mfma_f32_16x16x32_bf16(a1, b1, ob, 0, 0, 0);
  }
  float4v oacc = oa + ob;
  float* obase = OUT + ((size_t)(b * LQ + q0 + quad * 4)) * DH + wv * 16 + lm;
  obase[0 * DH] = oacc[0];
  obase[1 * DH] = oacc[1];
  obase[2 * DH] = oacc[2];
  obase[3 * DH] = oacc[3];
}

// ======================= fallback (no workspace) ============================
__global__ __launch_bounds__(256, 4)
void sdpa_fallback(const float* __restrict__ Q, const float* __restrict__ K,
                   const float* __restrict__ V, const int* __restrict__ KM,
                   const int* __restrict__ QM, float* __restrict__ OUT,
                   float* __restrict__ ATT)
{
  __shared__ short kvs[64 * VROW];
  __shared__ short scs[TQ * SSTR];
  const int bid  = blockIdx.x;
  const int wg   = ((bid & 7) << 9) | (bid >> 3);
  const int b    = wg >> 5;
  const int q0   = (wg & 31) * TQ;
  const int tid  = threadIdx.x;
  const int lane = tid & 63;
  const int wave = tid >> 6;
  const int lm   = lane & 15;
  const int quad = lane >> 4;
  const int row  = tid >> 4;
  const int col  = tid & 15;
  const size_t gro = (size_t)(b * LQ + q0 + row) * LK;
  int4v km8[8];
#pragma unroll
  for (int j = 0; j < 8; ++j)
    km8[j] = *(const int4v*)(KM + gro + col * 4 + j * 64);
  const float* qrow = Q + ((size_t)(b * LQ + q0 + lm)) * DH + quad * 8;
  short8v aq0, aq1;
  {
    float4v f0 = *(const float4v*)(qrow + 0);
    float4v f1 = *(const float4v*)(qrow + 4);
    float4v f2 = *(const float4v*)(qrow + 32);
    float4v f3 = *(const float4v*)(qrow + 36);
#pragma unroll
    for (int e = 0; e < 4; ++e) {
      aq0[e] = bf16r(f0[e]); aq0[e + 4] = bf16r(f1[e]);
      aq1[e] = bf16r(f2[e]); aq1[e + 4] = bf16r(f3[e]);
    }
  }
  unsigned kbm = 0;
#pragma unroll
  for (int j = 0; j < 8; ++j)
#pragma unroll
    for (int e = 0; e < 4; ++e) kbm |= (unsigned)(km8[j][e] != 0) << (j * 4 + e);
  const float* kbp = K + ((size_t)(b * LK + lm)) * DH + quad * 8;
#pragma unroll
  for (int t = 0; t < 8; ++t) {
    const float* kr = kbp + (size_t)(wave * 8 + t) * 16 * DH;
    float4v f0 = *(const float4v*)(kr + 0);
    float4v f1 = *(const float4v*)(kr + 4);
    float4v f2 = *(const float4v*)(kr + 32);
    float4v f3 = *(const float4v*)(kr + 36);
    short8v b0, b1;
#pragma unroll
    for (int e = 0; e < 4; ++e) {
      b0[e] = bf16r(f0[e]); b0[e + 4] = bf16r(f1[e]);
      b1[e] = bf16r(f2[e]); b1[e + 4] = bf16r(f3[e]);
    }
    float4v acc = {0.f, 0.f, 0.f, 0.f};
    acc = __builtin_amdgcn_mfma_f32_16x16x32_bf16(aq0, b0, acc, 0, 0, 0);
    acc = __builtin_amdgcn_mfma_f32_16x16x32_bf16(aq1, b1, acc, 0, 0, 0);
    const int n = (wave * 8 + t) * 16 + lm;
#pragma unroll
    for (int j = 0; j < 4; ++j)
      *(_Float16*)&scs[(quad * 4 + j) * SSTR + n] = (_Float16)acc[j];
  }
  int4v qm8[8];
#pragma unroll
  for (int j = 0; j < 8; ++j)
    qm8[j] = *(const int4v*)(QM + gro + col * 4 + j * 64);
  __syncthreads();
  float s[32];
  float mx = -INFINITY;
#pragma unroll
  for (int j = 0; j < 8; ++j) {
    half4v h4 = *(const half4v*)&scs[row * SSTR + col * 4 + j * 64];
#pragma unroll
    for (int e = 0; e < 4; ++e) {
      float val = ((kbm >> (j * 4 + e)) & 1u) ? -INFINITY : (float)h4[e];
      s[j * 4 + e] = val;
      mx = fmaxf(mx, val);
    }
  }
#pragma unroll
  for (int off = 8; off; off >>= 1) mx = fmaxf(mx, __shfl_xor(mx, off, 64));
  unsigned qbm = 0;
#pragma unroll
  for (int j = 0; j < 8; ++j)
#pragma unroll
    for (int e = 0; e < 4; ++e) qbm |= (unsigned)(qm8[j][e] != 0) << (j * 4 + e);
  float sum = 0.f;
#pragma unroll
  for (int j = 0; j < 32; ++j) {
    float p = __expf((s[j] - mx) * 0.125f);
    s[j] = p; sum += p;
  }
#pragma unroll
  for (int off = 8; off; off >>= 1) sum += __shfl_xor(sum, off, 64);
  const float inv = 1.f / sum;
  float* arow = ATT + gro;
#pragma unroll
  for (int j = 0; j < 8; ++j) {
    int kk = col * 4 + j * 64;
    float4v a4;
#pragma unroll
    for (int e = 0; e < 4; ++e)
      a4[e] = ((qbm >> (j * 4 + e)) & 1u) ? 0.f : s[j * 4 + e] * inv;
    *(float4v*)(arow + kk) = a4;
    short4v ab;
    ab[0] = bf16r(a4[0]); ab[1] = bf16r(a4[1]);
    ab[2] = bf16r(a4[2]); ab[3] = bf16r(a4[3]);
    *(short4v*)&scs[row * SSTR + kk] = ab;
  }
  float4v oacc = {0.f, 0.f, 0.f, 0.f};
  const float* vbase = V + ((size_t)b * LK) * DH;
#pragma unroll
  for (int kt = 0; kt < 8; ++kt) {
    const float* vp = vbase + (kt * 64 + row * 4) * DH + col * 4;
    float4v r0 = *(const float4v*)(vp);
    float4v r1 = *(const float4v*)(vp + DH);
    float4v r2 = *(const float4v*)(vp + 2 * DH);
    float4v r3 = *(const float4v*)(vp + 3 * DH);
#pragma unroll
    for (int e = 0; e < 4; ++e) {
      int d = col * 4 + e;
      int gp = row ^ (d & 15);
      short4v s4;
      s4[0] = bf16r(r0[e]); s4[1] = bf16r(r1[e]);
      s4[2] = bf16r(r2[e]); s4[3] = bf16r(r3[e]);
      *(short4v*)&kvs[d * VROW + gp * 4] = s4;
    }
    __syncthreads();
#pragma unroll
    for (int ks = 0; ks < 2; ++ks) {
      const short* ap = &scs[lm * SSTR + kt * 64 + ks * 32 + quad * 8];
      short8v a8 = *(const short8v*)ap;
      int n  = wave * 16 + lm;
      int g0 = ks * 8 + quad * 2;
      short4v lo = *(const short4v*)&kvs[n * VROW + ((g0) ^ (n & 15)) * 4];
      short4v hi = *(const short4v*)&kvs[n * VROW + ((g0 + 1) ^ (n & 15)) * 4];
      short8v b8;
      b8[0] = lo[0]; b8[1] = lo[1]; b8[2] = lo[2]; b8[3] = lo[3];
      b8[4] = hi[0]; b8[5] = hi[1]; b8[6] = hi[2]; b8[7] = hi[3];
      oacc = __builtin_amdgcn_mfma_f32_16x16x32_bf16(a8, b8, oacc, 0, 0, 0);
    }
    __syncthreads();
  }
  float* obase = OUT + ((size_t)(b * LQ + q0 + quad * 4)) * DH + wave * 16 + lm;
  obase[0 * DH] = oacc[0];
  obase[1 * DH] = oacc[1];
  obase[2 * DH] = oacc[2];
  obase[3 * DH] = oacc[3];
}

extern "C" void kernel_launch(void* const* d_in, const int* in_sizes, int n_in,
                              void* d_out, int out_size, void* d_ws, size_t ws_size,
                              hipStream_t stream) {
  const float* q  = (const float*)d_in[0];
  const float* k  = (const float*)d_in[1];
  const float* v  = (const float*)d_in[2];
  const int*   km = (const int*)d_in[3];
  const int*   qm = (const int*)d_in[4];
  float* out  = (float*)d_out;
  float* attn = out + (size_t)BATCH * LQ * DH;
  if (d_ws != nullptr && ws_size >= WS_BYTES_FULL) {
    short* ws = (short*)d_ws;
    const unsigned* kmb = (const unsigned*)(ws + WS_MB_SHORT);
    const unsigned* qmb = kmb + 1048576;
    hipLaunchKernelGGL(prep_kernel, dim3(3328), dim3(256), 0, stream,
                       q, k, v, km, qm, ws);
    hipLaunchKernelGGL(sdpa_main_packed, dim3(BATCH * (LQ / TQ)), dim3(256), 0,
                       stream, ws + WS_K, ws + WS_V, ws + WS_Q, kmb, qmb,
                       out, attn);
  } else if (d_ws != nullptr && ws_size >= WS_BYTES_QKV) {
    short* ws = (short*)d_ws;
    hipLaunchKernelGGL(prep_kernel, dim3(1280), dim3(256), 0, stream,
                       q, k, v, km, qm, ws);
    hipLaunchKernelGGL(sdpa_main_raw, dim3(BATCH * (LQ / TQ)), dim3(256), 0,
                       stream, ws + WS_K, ws + WS_V, ws + WS_Q, km, qm,
                       out, attn);
  } else {
    hipLaunchKernelGGL(sdpa_fallback, dim3(BATCH * (LQ / TQ)), dim3(256), 0,
                       stream, q, k, v, km, qm, out, attn);
  }
}

// Round 5
// 412.227 us; speedup vs baseline: 1.0854x; 1.0854x over previous
//
#include <hip/hip_runtime.h>
#include <hip/hip_bf16.h>

#define BATCH 128
#define LQ    512
#define LK    512
#define DH    64
#define TQ    16
#define SSTR  520   // bf16 attn overlay stride (verified bank-minimal b64 w / b128 r)
#define VROW  72    // prologue transpose tile stride (verified)

// workspace layout (shorts): Kbf[128][512][64] | Vt[128][64][512] | Qbf[128][512][64]
// then (dwords) KMb[128*512*16] | QMb[128*512*16]  (consumer-lane-order bitmasks)
#define WS_K 0
#define WS_V 4194304
#define WS_Q 8388608
#define WS_MB_SHORT 12582912          // short offset where dword masks begin
#define WS_BYTES_QKV 25165824ull      // K/V/Q only (raw-mask mid path)
#define WS_BYTES_FULL 33554432ull     // + 2 x 4 MB packed masks

typedef float    float4v __attribute__((ext_vector_type(4)));
typedef short    short8v __attribute__((ext_vector_type(8)));
typedef short    short4v __attribute__((ext_vector_type(4)));
typedef int      int4v   __attribute__((ext_vector_type(4)));
typedef _Float16 half4v  __attribute__((ext_vector_type(4)));

__device__ __forceinline__ short bf16r(float f) {
  union { float f; unsigned u; } x; x.f = f;
  unsigned r = x.u + 0x7FFFu + ((x.u >> 16) & 1u);
  return (short)(r >> 16);
}

// ========= prologue: K/Q->bf16, V->Vt bf16, masks->lane-order bits ==========
// grid 3328 (full) or 1280 (no mask packing):
//   [0,1024)      V transpose tiles
//   [1024,1152)   K convert     [1152,1280) Q convert
//   [1280,2304)   KM bit-pack   [2304,3328) QM bit-pack
__global__ __launch_bounds__(256)
void prep_kernel(const float* __restrict__ Q, const float* __restrict__ K,
                 const float* __restrict__ V, const int* __restrict__ KM,
                 const int* __restrict__ QM, short* __restrict__ ws)
{
  const int bid = blockIdx.x, tid = threadIdx.x;
  if (bid < 1024) {
    // ---- V transpose: one 64k x 64d tile -> Vt[b][d][k] --------------------
    __shared__ short T[64 * VROW];
    const int b  = bid >> 3;
    const int k0 = (bid & 7) * 64;
    const int bR = tid >> 4;
    const int bC = tid & 15;
    const float* vp = V + ((size_t)(b * LK + k0 + bR * 4)) * DH + bC * 4;
    float4v r0 = *(const float4v*)(vp);
    float4v r1 = *(const float4v*)(vp + DH);
    float4v r2 = *(const float4v*)(vp + 2 * DH);
    float4v r3 = *(const float4v*)(vp + 3 * DH);
#pragma unroll
    for (int e = 0; e < 4; ++e) {
      int d  = bC * 4 + e;
      int gp = bR ^ (d & 15);
      short4v s4;
      s4[0] = bf16r(r0[e]); s4[1] = bf16r(r1[e]);
      s4[2] = bf16r(r2[e]); s4[3] = bf16r(r3[e]);
      *(short4v*)&T[d * VROW + gp * 4] = s4;
    }
    __syncthreads();
    const int d  = tid >> 2;
    const int g0 = (tid & 3) * 4;
    short v16[16];
#pragma unroll
    for (int s2 = 0; s2 < 4; ++s2) {
      int g = g0 + s2;
      short4v t4 = *(const short4v*)&T[d * VROW + ((g ^ (d & 15)) * 4)];
      v16[s2 * 4 + 0] = t4[0]; v16[s2 * 4 + 1] = t4[1];
      v16[s2 * 4 + 2] = t4[2]; v16[s2 * 4 + 3] = t4[3];
    }
    short* dst = ws + WS_V + ((size_t)(b * DH + d)) * LK + k0 + g0 * 4;
    *(short8v*)(dst)     = *(short8v*)&v16[0];
    *(short8v*)(dst + 8) = *(short8v*)&v16[8];
  } else if (bid < 1280) {
    // ---- K / Q convert ----------------------------------------------------
    const bool isK = (bid < 1152);
    const size_t base = (size_t)((isK ? bid - 1024 : bid - 1152)) * 32768;
    const float* src = (isK ? K : Q) + base;
    short* dst = ws + (isK ? WS_K : WS_Q) + base;
#pragma unroll 4
    for (int u = 0; u < 32; ++u) {
      float4v f = *(const float4v*)(src + u * 1024 + tid * 4);
      short4v s4;
      s4[0] = bf16r(f[0]); s4[1] = bf16r(f[1]);
      s4[2] = bf16r(f[2]); s4[3] = bf16r(f[3]);
      *(short4v*)(dst + u * 1024 + tid * 4) = s4;
    }
  } else {
    // ---- mask bit-pack: coalesced loads + wave ballot ----------------------
    // Load j: lane reads src[j*64+lane] (coalesced 256B) -> ballot = 64-bit
    // mask for keys j*64..j*64+63 in key order. Consumer dword (wv,quad) with
    // bit t*4+e <-> key wv*128+t*16+quad*4+e is a bit-gather from ballots
    // B[2wv] (t=0..3) and B[2wv+1] (t=4..7): nibbles at quad*4 + 16u.
    const bool isKM = (bid < 2304);
    const int  mi   = bid - (isKM ? 1280 : 2304);
    const int  b    = mi >> 3;
    const int  q0   = (mi & 7) * 64 + (tid >> 6) * 16;   // this wave's 16 rows
    const int  lane = tid & 63;
    const int* srcb = (isKM ? KM : QM);
    unsigned*  mb   = (unsigned*)(ws + WS_MB_SHORT) + (isKM ? 0u : 1048576u);
    const int  wvq  = lane & 15;           // writer lanes: wv*4+quad
    const int  wv   = wvq >> 2;
    const int  quad = wvq & 3;
#pragma unroll 2
    for (int r = 0; r < 16; ++r) {
      const size_t qg  = (size_t)(b * LQ + q0 + r);
      const int*   src = srcb + qg * LK;
      unsigned long long B[8];
#pragma unroll
      for (int j = 0; j < 8; ++j) {
        int m = __builtin_nontemporal_load(src + j * 64 + lane);
        B[j] = __ballot(m != 0);
      }
      if (lane < 16) {
        unsigned long long blo = (B[2 * wv]     >> (quad * 4)) & 0x000F000F000F000FULL;
        unsigned long long bhi = (B[2 * wv + 1] >> (quad * 4)) & 0x000F000F000F000FULL;
        unsigned lo = (unsigned)((blo | (blo >> 12) | (blo >> 24) | (blo >> 36)) & 0xFFFFull);
        unsigned hi = (unsigned)((bhi | (bhi >> 12) | (bhi >> 24) | (bhi >> 36)) & 0xFFFFull);
        mb[qg * 16 + wvq] = lo | (hi << 16);
      }
    }
  }
}

// ============== main (packed masks): swapped-QK^T, reg softmax ==============
__global__ __launch_bounds__(256, 4)
void sdpa_main_packed(const short* __restrict__ Kbf, const short* __restrict__ Vt,
                      const short* __restrict__ Qbf,
                      const unsigned* __restrict__ KMB,
                      const unsigned* __restrict__ QMB,
                      float* __restrict__ OUT, float* __restrict__ ATT)
{
  __shared__ short sc[TQ * SSTR];    // bf16 attn (only LDS tile)
  __shared__ float cmb[2][64];       // cross-wave max / sum partials

  const int bid  = blockIdx.x;
  const int wg   = ((bid & 7) << 9) | (bid >> 3);   // XCD-contiguous, bijective
  const int b    = wg >> 5;
  const int q0   = (wg & 31) * TQ;
  const int tid  = threadIdx.x;
  const int lane = tid & 63;
  const int wv   = tid >> 6;
  const int lm   = lane & 15;
  const int quad = lane >> 4;

  const size_t qg    = (size_t)(b * LQ + q0 + lm);
  const size_t mbase = qg * LK + wv * 128 + quad * 4;

  // one dword per mask per lane -- the whole mask chain
  const unsigned kb  = KMB[qg * 16 + wv * 4 + quad];
  const unsigned qmb = QMB[qg * 16 + wv * 4 + quad];

  // Q B-fragments: two 16B bf16 loads (prepped)
  const short* qp = Qbf + qg * DH + quad * 8;
  const short8v qb0 = *(const short8v*)(qp);
  const short8v qb1 = *(const short8v*)(qp + 32);

  // ---------------- phase 1: S^T tiles, scores stay in registers ----------
  float s[32];
  const short* kp0 = Kbf + ((size_t)(b * LK + wv * 128 + lm)) * DH + quad * 8;
#pragma unroll
  for (int t = 0; t < 8; ++t) {
    const short* kp = kp0 + (size_t)t * 16 * DH;
    short8v ka0 = *(const short8v*)(kp);
    short8v ka1 = *(const short8v*)(kp + 32);
    float4v acc = {0.f, 0.f, 0.f, 0.f};
    acc = __builtin_amdgcn_mfma_f32_16x16x32_bf16(ka0, qb0, acc, 0, 0, 0);
    acc = __builtin_amdgcn_mfma_f32_16x16x32_bf16(ka1, qb1, acc, 0, 0, 0);
#pragma unroll
    for (int j = 0; j < 4; ++j) s[t * 4 + j] = acc[j];
  }

  // ---------------- phase 2: masks + softmax (in-register) ----------------
  float mx0 = -INFINITY, mx1 = -INFINITY, mx2 = -INFINITY, mx3 = -INFINITY;
#pragma unroll
  for (int t = 0; t < 8; ++t) {
#pragma unroll
    for (int e = 0; e < 4; ++e) {
      float v = ((kb >> (t * 4 + e)) & 1u) ? -INFINITY : s[t * 4 + e];
      s[t * 4 + e] = v;
      if (e == 0) mx0 = fmaxf(mx0, v);
      else if (e == 1) mx1 = fmaxf(mx1, v);
      else if (e == 2) mx2 = fmaxf(mx2, v);
      else mx3 = fmaxf(mx3, v);
    }
  }
  float mx = fmaxf(fmaxf(mx0, mx1), fmaxf(mx2, mx3));
  mx = fmaxf(mx, __shfl_xor(mx, 16, 64));
  mx = fmaxf(mx, __shfl_xor(mx, 32, 64));
  if (lane < 16) cmb[0][wv * 16 + lane] = mx;
  __syncthreads();
  mx = fmaxf(fmaxf(cmb[0][lm], cmb[0][16 + lm]),
             fmaxf(cmb[0][32 + lm], cmb[0][48 + lm]));

  float s0 = 0.f, s1 = 0.f, s2 = 0.f, s3 = 0.f;
#pragma unroll
  for (int t = 0; t < 8; ++t) {
    float p0 = __expf((s[t * 4 + 0] - mx) * 0.125f);
    float p1 = __expf((s[t * 4 + 1] - mx) * 0.125f);
    float p2 = __expf((s[t * 4 + 2] - mx) * 0.125f);
    float p3 = __expf((s[t * 4 + 3] - mx) * 0.125f);
    s[t * 4 + 0] = p0; s[t * 4 + 1] = p1;
    s[t * 4 + 2] = p2; s[t * 4 + 3] = p3;
    s0 += p0; s1 += p1; s2 += p2; s3 += p3;
  }
  float sum = (s0 + s1) + (s2 + s3);
  sum += __shfl_xor(sum, 16, 64);
  sum += __shfl_xor(sum, 32, 64);
  if (lane < 16) cmb[1][wv * 16 + lane] = sum;
  __syncthreads();
  sum = (cmb[1][lm] + cmb[1][16 + lm]) + (cmb[1][32 + lm] + cmb[1][48 + lm]);
  const float inv = __builtin_amdgcn_rcpf(sum);

  // ATT store (plain: L2 merges t/t+1 64B halves into full lines) + overlay
  float* arow = ATT + mbase;
  short* srow = &sc[lm * SSTR + wv * 128 + quad * 4];
#pragma unroll
  for (int t = 0; t < 8; ++t) {
    float4v a4;
#pragma unroll
    for (int e = 0; e < 4; ++e)
      a4[e] = ((qmb >> (t * 4 + e)) & 1u) ? 0.f : s[t * 4 + e] * inv;
    *(float4v*)(arow + t * 16) = a4;
    short4v ab;
    ab[0] = bf16r(a4[0]); ab[1] = bf16r(a4[1]);
    ab[2] = bf16r(a4[2]); ab[3] = bf16r(a4[3]);
    *(short4v*)(srow + t * 16) = ab;
  }
  __syncthreads();   // overlay complete before A-frag reads

  // ---------------- phase 3: O = A * Vt (barrier-free) --------------------
  float4v oa = {0.f, 0.f, 0.f, 0.f}, ob = {0.f, 0.f, 0.f, 0.f};
  const short* ap = &sc[lm * SSTR + quad * 8];
  const short* vp = Vt + ((size_t)(b * DH + wv * 16 + lm)) * LK + quad * 8;
#pragma unroll
  for (int c = 0; c < 16; c += 2) {
    short8v a0 = *(const short8v*)(ap + c * 32);
    short8v b0 = *(const short8v*)(vp + c * 32);
    short8v a1 = *(const short8v*)(ap + (c + 1) * 32);
    short8v b1 = *(const short8v*)(vp + (c + 1) * 32);
    oa = __builtin_amdgcn_mfma_f32_16x16x32_bf16(a0, b0, oa, 0, 0, 0);
    ob = __builtin_amdgcn_mfma_f32_16x16x32_bf16(a1, b1, ob, 0, 0, 0);
  }
  float4v oacc = oa + ob;
  float* obase = OUT + ((size_t)(b * LQ + q0 + quad * 4)) * DH + wv * 16 + lm;
  obase[0 * DH] = oacc[0];
  obase[1 * DH] = oacc[1];
  obase[2 * DH] = oacc[2];
  obase[3 * DH] = oacc[3];
}

// ============== main (raw masks): round-3 kernel, NT stores removed =========
__global__ __launch_bounds__(256, 4)
void sdpa_main_raw(const short* __restrict__ Kbf, const short* __restrict__ Vt,
                   const short* __restrict__ Qbf, const int* __restrict__ KM,
                   const int* __restrict__ QM, float* __restrict__ OUT,
                   float* __restrict__ ATT)
{
  __shared__ short sc[TQ * SSTR];
  __shared__ float cmb[2][64];
  const int bid  = blockIdx.x;
  const int wg   = ((bid & 7) << 9) | (bid >> 3);
  const int b    = wg >> 5;
  const int q0   = (wg & 31) * TQ;
  const int tid  = threadIdx.x;
  const int lane = tid & 63;
  const int wv   = tid >> 6;
  const int lm   = lane & 15;
  const int quad = lane >> 4;
  const size_t qg    = (size_t)(b * LQ + q0 + lm);
  const size_t mbase = qg * LK + wv * 128 + quad * 4;
  int4v kmv[8];
#pragma unroll
  for (int t = 0; t < 8; ++t)
    kmv[t] = __builtin_nontemporal_load((const int4v*)(KM + mbase + t * 16));
  const short* qp = Qbf + qg * DH + quad * 8;
  const short8v qb0 = *(const short8v*)(qp);
  const short8v qb1 = *(const short8v*)(qp + 32);
  float s[32];
  const short* kp0 = Kbf + ((size_t)(b * LK + wv * 128 + lm)) * DH + quad * 8;
#pragma unroll
  for (int t = 0; t < 8; ++t) {
    const short* kp = kp0 + (size_t)t * 16 * DH;
    short8v ka0 = *(const short8v*)(kp);
    short8v ka1 = *(const short8v*)(kp + 32);
    float4v acc = {0.f, 0.f, 0.f, 0.f};
    acc = __builtin_amdgcn_mfma_f32_16x16x32_bf16(ka0, qb0, acc, 0, 0, 0);
    acc = __builtin_amdgcn_mfma_f32_16x16x32_bf16(ka1, qb1, acc, 0, 0, 0);
#pragma unroll
    for (int j = 0; j < 4; ++j) s[t * 4 + j] = acc[j];
  }
  float mx = -INFINITY;
#pragma unroll
  for (int t = 0; t < 8; ++t)
#pragma unroll
    for (int e = 0; e < 4; ++e) {
      float v = kmv[t][e] ? -INFINITY : s[t * 4 + e];
      s[t * 4 + e] = v;
      mx = fmaxf(mx, v);
    }
  mx = fmaxf(mx, __shfl_xor(mx, 16, 64));
  mx = fmaxf(mx, __shfl_xor(mx, 32, 64));
  int4v qmv[8];
#pragma unroll
  for (int t = 0; t < 8; ++t)
    qmv[t] = __builtin_nontemporal_load((const int4v*)(QM + mbase + t * 16));
  if (lane < 16) cmb[0][wv * 16 + lane] = mx;
  __syncthreads();
  mx = fmaxf(fmaxf(cmb[0][lm], cmb[0][16 + lm]),
             fmaxf(cmb[0][32 + lm], cmb[0][48 + lm]));
  float sum = 0.f;
#pragma unroll
  for (int t = 0; t < 8; ++t)
#pragma unroll
    for (int e = 0; e < 4; ++e) {
      float p = __expf((s[t * 4 + e] - mx) * 0.125f);
      s[t * 4 + e] = p; sum += p;
    }
  sum += __shfl_xor(sum, 16, 64);
  sum += __shfl_xor(sum, 32, 64);
  if (lane < 16) cmb[1][wv * 16 + lane] = sum;
  __syncthreads();
  sum = (cmb[1][lm] + cmb[1][16 + lm]) + (cmb[1][32 + lm] + cmb[1][48 + lm]);
  const float inv = __builtin_amdgcn_rcpf(sum);
  float* arow = ATT + mbase;
  short* srow = &sc[lm * SSTR + wv * 128 + quad * 4];
#pragma unroll
  for (int t = 0; t < 8; ++t) {
    float4v a4;
#pragma unroll
    for (int e = 0; e < 4; ++e)
      a4[e] = qmv[t][e] ? 0.f : s[t * 4 + e] * inv;
    *(float4v*)(arow + t * 16) = a4;
    short4v ab;
    ab[0] = bf16r(a4[0]); ab[1] = bf16r(a4[1]);
    ab[2] = bf16r(a4[2]); ab[3] = bf16r(a4[3]);
    *(short4v*)(srow + t * 16) = ab;
  }
  __syncthreads();
  float4v oa = {0.f, 0.f, 0.f, 0.f}, ob = {0.f, 0.f, 0.f, 0.f};
  const short* ap = &sc[lm * SSTR + quad * 8];
  const short* vp = Vt + ((size_t)(b * DH + wv * 16 + lm)) * LK + quad * 8;
#pragma unroll
  for (int c = 0; c < 16; c += 2) {
    short8v a0 = *(const short8v*)(ap + c * 32);
    short8v b0 = *(const short8v*)(vp + c * 32);
    short8v a1 = *(const short8v*)(ap + (c + 1) * 32);
    short8v b1 = *(const short8v*)(vp + (c + 1) * 32);
    oa = __builtin_amdgcn_mfma_f32_16x16x32_bf16(a0, b0, oa, 0, 0, 0);
    ob = __builtin_amdgcn_mfma_f32_16x16x32_bf16(a1, b1, ob, 0, 0, 0);
  }
  float4v oacc = oa + ob;
  float* obase = OUT + ((size_t)(b * LQ + q0 + quad * 4)) * DH + wv * 16 + lm;
  obase[0 * DH] = oacc[0];
  obase[1 * DH] = oacc[1];
  obase[2 * DH] = oacc[2];
  obase[3 * DH] = oacc[3];
}

// ======================= fallback (no workspace) ============================
__global__ __launch_bounds__(256, 4)
void sdpa_fallback(const float* __restrict__ Q, const float* __restrict__ K,
                   const float* __restrict__ V, const int* __restrict__ KM,
                   const int* __restrict__ QM, float* __restrict__ OUT,
                   float* __restrict__ ATT)
{
  __shared__ short kvs[64 * VROW];
  __shared__ short scs[TQ * SSTR];
  const int bid  = blockIdx.x;
  const int wg   = ((bid & 7) << 9) | (bid >> 3);
  const int b    = wg >> 5;
  const int q0   = (wg & 31) * TQ;
  const int tid  = threadIdx.x;
  const int lane = tid & 63;
  const int wave = tid >> 6;
  const int lm   = lane & 15;
  const int quad = lane >> 4;
  const int row  = tid >> 4;
  const int col  = tid & 15;
  const size_t gro = (size_t)(b * LQ + q0 + row) * LK;
  int4v km8[8];
#pragma unroll
  for (int j = 0; j < 8; ++j)
    km8[j] = *(const int4v*)(KM + gro + col * 4 + j * 64);
  const float* qrow = Q + ((size_t)(b * LQ + q0 + lm)) * DH + quad * 8;
  short8v aq0, aq1;
  {
    float4v f0 = *(const float4v*)(qrow + 0);
    float4v f1 = *(const float4v*)(qrow + 4);
    float4v f2 = *(const float4v*)(qrow + 32);
    float4v f3 = *(const float4v*)(qrow + 36);
#pragma unroll
    for (int e = 0; e < 4; ++e) {
      aq0[e] = bf16r(f0[e]); aq0[e + 4] = bf16r(f1[e]);
      aq1[e] = bf16r(f2[e]); aq1[e + 4] = bf16r(f3[e]);
    }
  }
  unsigned kbm = 0;
#pragma unroll
  for (int j = 0; j < 8; ++j)
#pragma unroll
    for (int e = 0; e < 4; ++e) kbm |= (unsigned)(km8[j][e] != 0) << (j * 4 + e);
  const float* kbp = K + ((size_t)(b * LK + lm)) * DH + quad * 8;
#pragma unroll
  for (int t = 0; t < 8; ++t) {
    const float* kr = kbp + (size_t)(wave * 8 + t) * 16 * DH;
    float4v f0 = *(const float4v*)(kr + 0);
    float4v f1 = *(const float4v*)(kr + 4);
    float4v f2 = *(const float4v*)(kr + 32);
    float4v f3 = *(const float4v*)(kr + 36);
    short8v b0, b1;
#pragma unroll
    for (int e = 0; e < 4; ++e) {
      b0[e] = bf16r(f0[e]); b0[e + 4] = bf16r(f1[e]);
      b1[e] = bf16r(f2[e]); b1[e + 4] = bf16r(f3[e]);
    }
    float4v acc = {0.f, 0.f, 0.f, 0.f};
    acc = __builtin_amdgcn_mfma_f32_16x16x32_bf16(aq0, b0, acc, 0, 0, 0);
    acc = __builtin_amdgcn_mfma_f32_16x16x32_bf16(aq1, b1, acc, 0, 0, 0);
    const int n = (wave * 8 + t) * 16 + lm;
#pragma unroll
    for (int j = 0; j < 4; ++j)
      *(_Float16*)&scs[(quad * 4 + j) * SSTR + n] = (_Float16)acc[j];
  }
  int4v qm8[8];
#pragma unroll
  for (int j = 0; j < 8; ++j)
    qm8[j] = *(const int4v*)(QM + gro + col * 4 + j * 64);
  __syncthreads();
  float s[32];
  float mx = -INFINITY;
#pragma unroll
  for (int j = 0; j < 8; ++j) {
    half4v h4 = *(const half4v*)&scs[row * SSTR + col * 4 + j * 64];
#pragma unroll
    for (int e = 0; e < 4; ++e) {
      float val = ((kbm >> (j * 4 + e)) & 1u) ? -INFINITY : (float)h4[e];
      s[j * 4 + e] = val;
      mx = fmaxf(mx, val);
    }
  }
#pragma unroll
  for (int off = 8; off; off >>= 1) mx = fmaxf(mx, __shfl_xor(mx, off, 64));
  unsigned qbm = 0;
#pragma unroll
  for (int j = 0; j < 8; ++j)
#pragma unroll
    for (int e = 0; e < 4; ++e) qbm |= (unsigned)(qm8[j][e] != 0) << (j * 4 + e);
  float sum = 0.f;
#pragma unroll
  for (int j = 0; j < 32; ++j) {
    float p = __expf((s[j] - mx) * 0.125f);
    s[j] = p; sum += p;
  }
#pragma unroll
  for (int off = 8; off; off >>= 1) sum += __shfl_xor(sum, off, 64);
  const float inv = 1.f / sum;
  float* arow = ATT + gro;
#pragma unroll
  for (int j = 0; j < 8; ++j) {
    int kk = col * 4 + j * 64;
    float4v a4;
#pragma unroll
    for (int e = 0; e < 4; ++e)
      a4[e] = ((qbm >> (j * 4 + e)) & 1u) ? 0.f : s[j * 4 + e] * inv;
    *(float4v*)(arow + kk) = a4;
    short4v ab;
    ab[0] = bf16r(a4[0]); ab[1] = bf16r(a4[1]);
    ab[2] = bf16r(a4[2]); ab[3] = bf16r(a4[3]);
    *(short4v*)&scs[row * SSTR + kk] = ab;
  }
  float4v oacc = {0.f, 0.f, 0.f, 0.f};
  const float* vbase = V + ((size_t)b * LK) * DH;
#pragma unroll
  for (int kt = 0; kt < 8; ++kt) {
    const float* vp = vbase + (kt * 64 + row * 4) * DH + col * 4;
    float4v r0 = *(const float4v*)(vp);
    float4v r1 = *(const float4v*)(vp + DH);
    float4v r2 = *(const float4v*)(vp + 2 * DH);
    float4v r3 = *(const float4v*)(vp + 3 * DH);
#pragma unroll
    for (int e = 0; e < 4; ++e) {
      int d = col * 4 + e;
      int gp = row ^ (d & 15);
      short4v s4;
      s4[0] = bf16r(r0[e]); s4[1] = bf16r(r1[e]);
      s4[2] = bf16r(r2[e]); s4[3] = bf16r(r3[e]);
      *(short4v*)&kvs[d * VROW + gp * 4] = s4;
    }
    __syncthreads();
#pragma unroll
    for (int ks = 0; ks < 2; ++ks) {
      const short* ap = &scs[lm * SSTR + kt * 64 + ks * 32 + quad * 8];
      short8v a8 = *(const short8v*)ap;
      int n  = wave * 16 + lm;
      int g0 = ks * 8 + quad * 2;
      short4v lo = *(const short4v*)&kvs[n * VROW + ((g0) ^ (n & 15)) * 4];
      short4v hi = *(const short4v*)&kvs[n * VROW + ((g0 + 1) ^ (n & 15)) * 4];
      short8v b8;
      b8[0] = lo[0]; b8[1] = lo[1]; b8[2] = lo[2]; b8[3] = lo[3];
      b8[4] = hi[0]; b8[5] = hi[1]; b8[6] = hi[2]; b8[7] = hi[3];
      oacc = __builtin_amdgcn_mfma_f32_16x16x32_bf16(a8, b8, oacc, 0, 0, 0);
    }
    __syncthreads();
  }
  float* obase = OUT + ((size_t)(b * LQ + q0 + quad * 4)) * DH + wave * 16 + lm;
  obase[0 * DH] = oacc[0];
  obase[1 * DH] = oacc[1];
  obase[2 * DH] = oacc[2];
  obase[3 * DH] = oacc[3];
}

extern "C" void kernel_launch(void* const* d_in, const int* in_sizes, int n_in,
                              void* d_out, int out_size, void* d_ws, size_t ws_size,
                              hipStream_t stream) {
  const float* q  = (const float*)d_in[0];
  const float* k  = (const float*)d_in[1];
  const float* v  = (const float*)d_in[2];
  const int*   km = (const int*)d_in[3];
  const int*   qm = (const int*)d_in[4];
  float* out  = (float*)d_out;
  float* attn = out + (size_t)BATCH * LQ * DH;
  if (d_ws != nullptr && ws_size >= WS_BYTES_FULL) {
    short* ws = (short*)d_ws;
    const unsigned* kmb = (const unsigned*)(ws + WS_MB_SHORT);
    const unsigned* qmb = kmb + 1048576;
    hipLaunchKernelGGL(prep_kernel, dim3(3328), dim3(256), 0, stream,
                       q, k, v, km, qm, ws);
    hipLaunchKernelGGL(sdpa_main_packed, dim3(BATCH * (LQ / TQ)), dim3(256), 0,
                       stream, ws + WS_K, ws + WS_V, ws + WS_Q, kmb, qmb,
                       out, attn);
  } else if (d_ws != nullptr && ws_size >= WS_BYTES_QKV) {
    short* ws = (short*)d_ws;
    hipLaunchKernelGGL(prep_kernel, dim3(1280), dim3(256), 0, stream,
                       q, k, v, km, qm, ws);
    hipLaunchKernelGGL(sdpa_main_raw, dim3(BATCH * (LQ / TQ)), dim3(256), 0,
                       stream, ws + WS_K, ws + WS_V, ws + WS_Q, km, qm,
                       out, attn);
  } else {
    hipLaunchKernelGGL(sdpa_fallback, dim3(BATCH * (LQ / TQ)), dim3(256), 0,
                       stream, q, k, v, km, qm, out, attn);
  }
}

// Round 6
// 403.426 us; speedup vs baseline: 1.1091x; 1.0218x over previous
//
#include <hip/hip_runtime.h>
#include <hip/hip_bf16.h>

#define BATCH 128
#define LQ    512
#define LK    512
#define DH    64
#define TQ    16
#define SSTR  520   // bf16 attn overlay stride (verified bank-minimal b64 w / b128 r)
#define VROW  72    // prologue transpose tile stride (verified)

// workspace layout (shorts): Kbf[128][512][64] | Vt[128][64][512] | Qbf[128][512][64]
#define WS_K 0
#define WS_V 4194304
#define WS_Q 8388608
#define WS_BYTES_QKV 25165824ull

typedef float    float4v __attribute__((ext_vector_type(4)));
typedef short    short8v __attribute__((ext_vector_type(8)));
typedef short    short4v __attribute__((ext_vector_type(4)));
typedef int      int4v   __attribute__((ext_vector_type(4)));
typedef _Float16 half4v  __attribute__((ext_vector_type(4)));

__device__ __forceinline__ short bf16r(float f) {
  union { float f; unsigned u; } x; x.f = f;
  unsigned r = x.u + 0x7FFFu + ((x.u >> 16) & 1u);
  return (short)(r >> 16);
}

// ========= prologue: K/Q->bf16, V->Vt bf16 (masks handled in main) ==========
// grid 1280: [0,1024) V transpose | [1024,1152) K convert | [1152,1280) Q convert
__global__ __launch_bounds__(256)
void prep_kernel(const float* __restrict__ Q, const float* __restrict__ K,
                 const float* __restrict__ V, short* __restrict__ ws)
{
  const int bid = blockIdx.x, tid = threadIdx.x;
  if (bid < 1024) {
    // ---- V transpose: one 64k x 64d tile -> Vt[b][d][k] --------------------
    __shared__ short T[64 * VROW];
    const int b  = bid >> 3;
    const int k0 = (bid & 7) * 64;
    const int bR = tid >> 4;
    const int bC = tid & 15;
    const float* vp = V + ((size_t)(b * LK + k0 + bR * 4)) * DH + bC * 4;
    float4v r0 = __builtin_nontemporal_load((const float4v*)(vp));
    float4v r1 = __builtin_nontemporal_load((const float4v*)(vp + DH));
    float4v r2 = __builtin_nontemporal_load((const float4v*)(vp + 2 * DH));
    float4v r3 = __builtin_nontemporal_load((const float4v*)(vp + 3 * DH));
#pragma unroll
    for (int e = 0; e < 4; ++e) {
      int d  = bC * 4 + e;
      int gp = bR ^ (d & 15);
      short4v s4;
      s4[0] = bf16r(r0[e]); s4[1] = bf16r(r1[e]);
      s4[2] = bf16r(r2[e]); s4[3] = bf16r(r3[e]);
      *(short4v*)&T[d * VROW + gp * 4] = s4;
    }
    __syncthreads();
    const int d  = tid >> 2;
    const int g0 = (tid & 3) * 4;
    short v16[16];
#pragma unroll
    for (int s2 = 0; s2 < 4; ++s2) {
      int g = g0 + s2;
      short4v t4 = *(const short4v*)&T[d * VROW + ((g ^ (d & 15)) * 4)];
      v16[s2 * 4 + 0] = t4[0]; v16[s2 * 4 + 1] = t4[1];
      v16[s2 * 4 + 2] = t4[2]; v16[s2 * 4 + 3] = t4[3];
    }
    short* dst = ws + WS_V + ((size_t)(b * DH + d)) * LK + k0 + g0 * 4;
    *(short8v*)(dst)     = *(short8v*)&v16[0];
    *(short8v*)(dst + 8) = *(short8v*)&v16[8];
  } else {
    // ---- K / Q convert ----------------------------------------------------
    const bool isK = (bid < 1152);
    const size_t base = (size_t)((isK ? bid - 1024 : bid - 1152)) * 32768;
    const float* src = (isK ? K : Q) + base;
    short* dst = ws + (isK ? WS_K : WS_Q) + base;
#pragma unroll 4
    for (int u = 0; u < 32; ++u) {
      float4v f = __builtin_nontemporal_load((const float4v*)(src + u * 1024 + tid * 4));
      short4v s4;
      s4[0] = bf16r(f[0]); s4[1] = bf16r(f[1]);
      s4[2] = bf16r(f[2]); s4[3] = bf16r(f[3]);
      *(short4v*)(dst + u * 1024 + tid * 4) = s4;
    }
  }
}

// ===== main: in-block ballot mask pack + swapped-QK^T + reg softmax =========
__global__ __launch_bounds__(256, 6)
void sdpa_fused(const short* __restrict__ Kbf, const short* __restrict__ Vt,
                const short* __restrict__ Qbf, const int* __restrict__ KM,
                const int* __restrict__ QM,
                float* __restrict__ OUT, float* __restrict__ ATT)
{
  __shared__ short sc[TQ * SSTR];        // bf16 attn overlay
  __shared__ float cmb[2][64];           // cross-wave max / sum partials
  __shared__ unsigned pk[2][16][17];     // packed masks [mask][row][wv*4+quad], +1 pad

  const int bid  = blockIdx.x;
  const int wg   = ((bid & 7) << 9) | (bid >> 3);   // XCD-contiguous, bijective
  const int b    = wg >> 5;
  const int q0   = (wg & 31) * TQ;
  const int tid  = threadIdx.x;
  const int lane = tid & 63;
  const int wv   = tid >> 6;
  const int lm   = lane & 15;
  const int quad = lane >> 4;

  // ---- mask pack (verified ballot+nibble-gather, from R5 prep) ------------
  // wave wv packs rows wv*4..wv*4+3 for both masks; 8 coalesced NT scalar
  // loads + 8 ballots per row; writer lanes 0..15 emit one consumer dword.
#pragma unroll
  for (int m = 0; m < 2; ++m) {
    const int* srcb = m ? QM : KM;
#pragma unroll
    for (int r = 0; r < 4; ++r) {
      const int rr = wv * 4 + r;
      const int* src = srcb + ((size_t)(b * LQ + q0 + rr)) * LK;
      unsigned long long B[8];
#pragma unroll
      for (int j = 0; j < 8; ++j) {
        int mv = __builtin_nontemporal_load(src + j * 64 + lane);
        B[j] = __ballot(mv != 0);
      }
      if (lane < 16) {
        const int wvv = lane >> 2, qd = lane & 3;
        unsigned long long blo = (B[2 * wvv]     >> (qd * 4)) & 0x000F000F000F000FULL;
        unsigned long long bhi = (B[2 * wvv + 1] >> (qd * 4)) & 0x000F000F000F000FULL;
        unsigned lo = (unsigned)((blo | (blo >> 12) | (blo >> 24) | (blo >> 36)) & 0xFFFFull);
        unsigned hi = (unsigned)((bhi | (bhi >> 12) | (bhi >> 24) | (bhi >> 36)) & 0xFFFFull);
        pk[m][rr][lane] = lo | (hi << 16);
      }
    }
  }

  const size_t qg    = (size_t)(b * LQ + q0 + lm);
  const size_t mbase = qg * LK + wv * 128 + quad * 4;

  // Q B-fragments: two 16B bf16 loads (prepped)
  const short* qp = Qbf + qg * DH + quad * 8;
  const short8v qb0 = *(const short8v*)(qp);
  const short8v qb1 = *(const short8v*)(qp + 32);

  // ---------------- phase 1: S^T tiles, scores stay in registers ----------
  float s[32];
  const short* kp0 = Kbf + ((size_t)(b * LK + wv * 128 + lm)) * DH + quad * 8;
#pragma unroll
  for (int t = 0; t < 8; ++t) {
    const short* kp = kp0 + (size_t)t * 16 * DH;
    short8v ka0 = *(const short8v*)(kp);
    short8v ka1 = *(const short8v*)(kp + 32);
    float4v acc = {0.f, 0.f, 0.f, 0.f};
    acc = __builtin_amdgcn_mfma_f32_16x16x32_bf16(ka0, qb0, acc, 0, 0, 0);
    acc = __builtin_amdgcn_mfma_f32_16x16x32_bf16(ka1, qb1, acc, 0, 0, 0);
#pragma unroll
    for (int j = 0; j < 4; ++j) s[t * 4 + j] = acc[j];
  }

  __syncthreads();   // pk visible to all waves
  const unsigned kb  = pk[0][lm][wv * 4 + quad];
  const unsigned qmb = pk[1][lm][wv * 4 + quad];

  // ---------------- phase 2: masks + softmax (in-register) ----------------
  float mx0 = -INFINITY, mx1 = -INFINITY, mx2 = -INFINITY, mx3 = -INFINITY;
#pragma unroll
  for (int t = 0; t < 8; ++t) {
#pragma unroll
    for (int e = 0; e < 4; ++e) {
      float v = ((kb >> (t * 4 + e)) & 1u) ? -INFINITY : s[t * 4 + e];
      s[t * 4 + e] = v;
      if (e == 0) mx0 = fmaxf(mx0, v);
      else if (e == 1) mx1 = fmaxf(mx1, v);
      else if (e == 2) mx2 = fmaxf(mx2, v);
      else mx3 = fmaxf(mx3, v);
    }
  }
  float mx = fmaxf(fmaxf(mx0, mx1), fmaxf(mx2, mx3));
  mx = fmaxf(mx, __shfl_xor(mx, 16, 64));
  mx = fmaxf(mx, __shfl_xor(mx, 32, 64));
  if (lane < 16) cmb[0][wv * 16 + lane] = mx;
  __syncthreads();
  mx = fmaxf(fmaxf(cmb[0][lm], cmb[0][16 + lm]),
             fmaxf(cmb[0][32 + lm], cmb[0][48 + lm]));

  float s0 = 0.f, s1 = 0.f, s2 = 0.f, s3 = 0.f;
#pragma unroll
  for (int t = 0; t < 8; ++t) {
    float p0 = __expf((s[t * 4 + 0] - mx) * 0.125f);
    float p1 = __expf((s[t * 4 + 1] - mx) * 0.125f);
    float p2 = __expf((s[t * 4 + 2] - mx) * 0.125f);
    float p3 = __expf((s[t * 4 + 3] - mx) * 0.125f);
    s[t * 4 + 0] = p0; s[t * 4 + 1] = p1;
    s[t * 4 + 2] = p2; s[t * 4 + 3] = p3;
    s0 += p0; s1 += p1; s2 += p2; s3 += p3;
  }
  float sum = (s0 + s1) + (s2 + s3);
  sum += __shfl_xor(sum, 16, 64);
  sum += __shfl_xor(sum, 32, 64);
  if (lane < 16) cmb[1][wv * 16 + lane] = sum;
  __syncthreads();
  sum = (cmb[1][lm] + cmb[1][16 + lm]) + (cmb[1][32 + lm] + cmb[1][48 + lm]);
  const float inv = __builtin_amdgcn_rcpf(sum);

  // ATT store (plain: L2 merges 64B halves into full lines) + bf16 overlay
  float* arow = ATT + mbase;
  short* srow = &sc[lm * SSTR + wv * 128 + quad * 4];
#pragma unroll
  for (int t = 0; t < 8; ++t) {
    float4v a4;
#pragma unroll
    for (int e = 0; e < 4; ++e)
      a4[e] = ((qmb >> (t * 4 + e)) & 1u) ? 0.f : s[t * 4 + e] * inv;
    *(float4v*)(arow + t * 16) = a4;
    short4v ab;
    ab[0] = bf16r(a4[0]); ab[1] = bf16r(a4[1]);
    ab[2] = bf16r(a4[2]); ab[3] = bf16r(a4[3]);
    *(short4v*)(srow + t * 16) = ab;
  }
  __syncthreads();   // overlay complete before A-frag reads

  // ---------------- phase 3: O = A * Vt (barrier-free) --------------------
  float4v oa = {0.f, 0.f, 0.f, 0.f}, ob = {0.f, 0.f, 0.f, 0.f};
  const short* ap = &sc[lm * SSTR + quad * 8];
  const short* vp = Vt + ((size_t)(b * DH + wv * 16 + lm)) * LK + quad * 8;
#pragma unroll
  for (int c = 0; c < 16; c += 2) {
    short8v a0 = *(const short8v*)(ap + c * 32);
    short8v b0 = *(const short8v*)(vp + c * 32);
    short8v a1 = *(const short8v*)(ap + (c + 1) * 32);
    short8v b1 = *(const short8v*)(vp + (c + 1) * 32);
    oa = __builtin_amdgcn_mfma_f32_16x16x32_bf16(a0, b0, oa, 0, 0, 0);
    ob = __builtin_amdgcn_mfma_f32_16x16x32_bf16(a1, b1, ob, 0, 0, 0);
  }
  float4v oacc = oa + ob;
  float* obase = OUT + ((size_t)(b * LQ + q0 + quad * 4)) * DH + wv * 16 + lm;
  obase[0 * DH] = oacc[0];
  obase[1 * DH] = oacc[1];
  obase[2 * DH] = oacc[2];
  obase[3 * DH] = oacc[3];
}

// ======================= fallback (no workspace) ============================
__global__ __launch_bounds__(256, 4)
void sdpa_fallback(const float* __restrict__ Q, const float* __restrict__ K,
                   const float* __restrict__ V, const int* __restrict__ KM,
                   const int* __restrict__ QM, float* __restrict__ OUT,
                   float* __restrict__ ATT)
{
  __shared__ short kvs[64 * VROW];
  __shared__ short scs[TQ * SSTR];
  const int bid  = blockIdx.x;
  const int wg   = ((bid & 7) << 9) | (bid >> 3);
  const int b    = wg >> 5;
  const int q0   = (wg & 31) * TQ;
  const int tid  = threadIdx.x;
  const int lane = tid & 63;
  const int wave = tid >> 6;
  const int lm   = lane & 15;
  const int quad = lane >> 4;
  const int row  = tid >> 4;
  const int col  = tid & 15;
  const size_t gro = (size_t)(b * LQ + q0 + row) * LK;
  int4v km8[8];
#pragma unroll
  for (int j = 0; j < 8; ++j)
    km8[j] = *(const int4v*)(KM + gro + col * 4 + j * 64);
  const float* qrow = Q + ((size_t)(b * LQ + q0 + lm)) * DH + quad * 8;
  short8v aq0, aq1;
  {
    float4v f0 = *(const float4v*)(qrow + 0);
    float4v f1 = *(const float4v*)(qrow + 4);
    float4v f2 = *(const float4v*)(qrow + 32);
    float4v f3 = *(const float4v*)(qrow + 36);
#pragma unroll
    for (int e = 0; e < 4; ++e) {
      aq0[e] = bf16r(f0[e]); aq0[e + 4] = bf16r(f1[e]);
      aq1[e] = bf16r(f2[e]); aq1[e + 4] = bf16r(f3[e]);
    }
  }
  unsigned kbm = 0;
#pragma unroll
  for (int j = 0; j < 8; ++j)
#pragma unroll
    for (int e = 0; e < 4; ++e) kbm |= (unsigned)(km8[j][e] != 0) << (j * 4 + e);
  const float* kbp = K + ((size_t)(b * LK + lm)) * DH + quad * 8;
#pragma unroll
  for (int t = 0; t < 8; ++t) {
    const float* kr = kbp + (size_t)(wave * 8 + t) * 16 * DH;
    float4v f0 = *(const float4v*)(kr + 0);
    float4v f1 = *(const float4v*)(kr + 4);
    float4v f2 = *(const float4v*)(kr + 32);
    float4v f3 = *(const float4v*)(kr + 36);
    short8v b0, b1;
#pragma unroll
    for (int e = 0; e < 4; ++e) {
      b0[e] = bf16r(f0[e]); b0[e + 4] = bf16r(f1[e]);
      b1[e] = bf16r(f2[e]); b1[e + 4] = bf16r(f3[e]);
    }
    float4v acc = {0.f, 0.f, 0.f, 0.f};
    acc = __builtin_amdgcn_mfma_f32_16x16x32_bf16(aq0, b0, acc, 0, 0, 0);
    acc = __builtin_amdgcn_mfma_f32_16x16x32_bf16(aq1, b1, acc, 0, 0, 0);
    const int n = (wave * 8 + t) * 16 + lm;
#pragma unroll
    for (int j = 0; j < 4; ++j)
      *(_Float16*)&scs[(quad * 4 + j) * SSTR + n] = (_Float16)acc[j];
  }
  int4v qm8[8];
#pragma unroll
  for (int j = 0; j < 8; ++j)
    qm8[j] = *(const int4v*)(QM + gro + col * 4 + j * 64);
  __syncthreads();
  float s[32];
  float mx = -INFINITY;
#pragma unroll
  for (int j = 0; j < 8; ++j) {
    half4v h4 = *(const half4v*)&scs[row * SSTR + col * 4 + j * 64];
#pragma unroll
    for (int e = 0; e < 4; ++e) {
      float val = ((kbm >> (j * 4 + e)) & 1u) ? -INFINITY : (float)h4[e];
      s[j * 4 + e] = val;
      mx = fmaxf(mx, val);
    }
  }
#pragma unroll
  for (int off = 8; off; off >>= 1) mx = fmaxf(mx, __shfl_xor(mx, off, 64));
  unsigned qbm = 0;
#pragma unroll
  for (int j = 0; j < 8; ++j)
#pragma unroll
    for (int e = 0; e < 4; ++e) qbm |= (unsigned)(qm8[j][e] != 0) << (j * 4 + e);
  float sum = 0.f;
#pragma unroll
  for (int j = 0; j < 32; ++j) {
    float p = __expf((s[j] - mx) * 0.125f);
    s[j] = p; sum += p;
  }
#pragma unroll
  for (int off = 8; off; off >>= 1) sum += __shfl_xor(sum, off, 64);
  const float inv = 1.f / sum;
  float* arow = ATT + gro;
#pragma unroll
  for (int j = 0; j < 8; ++j) {
    int kk = col * 4 + j * 64;
    float4v a4;
#pragma unroll
    for (int e = 0; e < 4; ++e)
      a4[e] = ((qbm >> (j * 4 + e)) & 1u) ? 0.f : s[j * 4 + e] * inv;
    *(float4v*)(arow + kk) = a4;
    short4v ab;
    ab[0] = bf16r(a4[0]); ab[1] = bf16r(a4[1]);
    ab[2] = bf16r(a4[2]); ab[3] = bf16r(a4[3]);
    *(short4v*)&scs[row * SSTR + kk] = ab;
  }
  float4v oacc = {0.f, 0.f, 0.f, 0.f};
  const float* vbase = V + ((size_t)b * LK) * DH;
#pragma unroll
  for (int kt = 0; kt < 8; ++kt) {
    const float* vp = vbase + (kt * 64 + row * 4) * DH + col * 4;
    float4v r0 = *(const float4v*)(vp);
    float4v r1 = *(const float4v*)(vp + DH);
    float4v r2 = *(const float4v*)(vp + 2 * DH);
    float4v r3 = *(const float4v*)(vp + 3 * DH);
#pragma unroll
    for (int e = 0; e < 4; ++e) {
      int d = col * 4 + e;
      int gp = row ^ (d & 15);
      short4v s4;
      s4[0] = bf16r(r0[e]); s4[1] = bf16r(r1[e]);
      s4[2] = bf16r(r2[e]); s4[3] = bf16r(r3[e]);
      *(short4v*)&kvs[d * VROW + gp * 4] = s4;
    }
    __syncthreads();
#pragma unroll
    for (int ks = 0; ks < 2; ++ks) {
      const short* ap = &scs[lm * SSTR + kt * 64 + ks * 32 + quad * 8];
      short8v a8 = *(const short8v*)ap;
      int n  = wave * 16 + lm;
      int g0 = ks * 8 + quad * 2;
      short4v lo = *(const short4v*)&kvs[n * VROW + ((g0) ^ (n & 15)) * 4];
      short4v hi = *(const short4v*)&kvs[n * VROW + ((g0 + 1) ^ (n & 15)) * 4];
      short8v b8;
      b8[0] = lo[0]; b8[1] = lo[1]; b8[2] = lo[2]; b8[3] = lo[3];
      b8[4] = hi[0]; b8[5] = hi[1]; b8[6] = hi[2]; b8[7] = hi[3];
      oacc = __builtin_amdgcn_mfma_f32_16x16x32_bf16(a8, b8, oacc, 0, 0, 0);
    }
    __syncthreads();
  }
  float* obase = OUT + ((size_t)(b * LQ + q0 + quad * 4)) * DH + wave * 16 + lm;
  obase[0 * DH] = oacc[0];
  obase[1 * DH] = oacc[1];
  obase[2 * DH] = oacc[2];
  obase[3 * DH] = oacc[3];
}

extern "C" void kernel_launch(void* const* d_in, const int* in_sizes, int n_in,
                              void* d_out, int out_size, void* d_ws, size_t ws_size,
                              hipStream_t stream) {
  const float* q  = (const float*)d_in[0];
  const float* k  = (const float*)d_in[1];
  const float* v  = (const float*)d_in[2];
  const int*   km = (const int*)d_in[3];
  const int*   qm = (const int*)d_in[4];
  float* out  = (float*)d_out;
  float* attn = out + (size_t)BATCH * LQ * DH;
  if (d_ws != nullptr && ws_size >= WS_BYTES_QKV) {
    short* ws = (short*)d_ws;
    hipLaunchKernelGGL(prep_kernel, dim3(1280), dim3(256), 0, stream,
                       q, k, v, ws);
    hipLaunchKernelGGL(sdpa_fused, dim3(BATCH * (LQ / TQ)), dim3(256), 0,
                       stream, ws + WS_K, ws + WS_V, ws + WS_Q, km, qm,
                       out, attn);
  } else {
    hipLaunchKernelGGL(sdpa_fallback, dim3(BATCH * (LQ / TQ)), dim3(256), 0,
                       stream, q, k, v, km, qm, out, attn);
  }
}

// Round 7
// 396.291 us; speedup vs baseline: 1.1291x; 1.0180x over previous
//
#include <hip/hip_runtime.h>
#include <hip/hip_bf16.h>

#define BATCH 128
#define LQ    512
#define LK    512
#define DH    64
#define TQ    16
#define SSTR  520   // bf16 attn overlay stride (verified bank-minimal b64 w / b128 r)
#define VROW  72    // prologue transpose tile stride (verified)

// workspace layout (shorts): Kbf[128][512][64] | Vt[128][64][512] | Qbf[128][512][64]
#define WS_K 0
#define WS_V 4194304
#define WS_Q 8388608
#define WS_BYTES_QKV 25165824ull

typedef float    float4v __attribute__((ext_vector_type(4)));
typedef short    short8v __attribute__((ext_vector_type(8)));
typedef short    short4v __attribute__((ext_vector_type(4)));
typedef int      int4v   __attribute__((ext_vector_type(4)));
typedef _Float16 half4v  __attribute__((ext_vector_type(4)));

__device__ __forceinline__ short bf16r(float f) {
  union { float f; unsigned u; } x; x.f = f;
  unsigned r = x.u + 0x7FFFu + ((x.u >> 16) & 1u);
  return (short)(r >> 16);
}

// ========= prologue: K/Q->bf16, V->Vt bf16 (masks handled in main) ==========
// grid 1280: [0,1024) V transpose | [1024,1152) K convert | [1152,1280) Q convert
__global__ __launch_bounds__(256)
void prep_kernel(const float* __restrict__ Q, const float* __restrict__ K,
                 const float* __restrict__ V, short* __restrict__ ws)
{
  const int bid = blockIdx.x, tid = threadIdx.x;
  if (bid < 1024) {
    // ---- V transpose: one 64k x 64d tile -> Vt[b][d][k] --------------------
    __shared__ short T[64 * VROW];
    const int b  = bid >> 3;
    const int k0 = (bid & 7) * 64;
    const int bR = tid >> 4;
    const int bC = tid & 15;
    const float* vp = V + ((size_t)(b * LK + k0 + bR * 4)) * DH + bC * 4;
    float4v r0 = __builtin_nontemporal_load((const float4v*)(vp));
    float4v r1 = __builtin_nontemporal_load((const float4v*)(vp + DH));
    float4v r2 = __builtin_nontemporal_load((const float4v*)(vp + 2 * DH));
    float4v r3 = __builtin_nontemporal_load((const float4v*)(vp + 3 * DH));
#pragma unroll
    for (int e = 0; e < 4; ++e) {
      int d  = bC * 4 + e;
      int gp = bR ^ (d & 15);
      short4v s4;
      s4[0] = bf16r(r0[e]); s4[1] = bf16r(r1[e]);
      s4[2] = bf16r(r2[e]); s4[3] = bf16r(r3[e]);
      *(short4v*)&T[d * VROW + gp * 4] = s4;
    }
    __syncthreads();
    const int d  = tid >> 2;
    const int g0 = (tid & 3) * 4;
    short v16[16];
#pragma unroll
    for (int s2 = 0; s2 < 4; ++s2) {
      int g = g0 + s2;
      short4v t4 = *(const short4v*)&T[d * VROW + ((g ^ (d & 15)) * 4)];
      v16[s2 * 4 + 0] = t4[0]; v16[s2 * 4 + 1] = t4[1];
      v16[s2 * 4 + 2] = t4[2]; v16[s2 * 4 + 3] = t4[3];
    }
    short* dst = ws + WS_V + ((size_t)(b * DH + d)) * LK + k0 + g0 * 4;
    *(short8v*)(dst)     = *(short8v*)&v16[0];
    *(short8v*)(dst + 8) = *(short8v*)&v16[8];
  } else {
    // ---- K / Q convert ----------------------------------------------------
    const bool isK = (bid < 1152);
    const size_t base = (size_t)((isK ? bid - 1024 : bid - 1152)) * 32768;
    const float* src = (isK ? K : Q) + base;
    short* dst = ws + (isK ? WS_K : WS_Q) + base;
#pragma unroll 4
    for (int u = 0; u < 32; ++u) {
      float4v f = __builtin_nontemporal_load((const float4v*)(src + u * 1024 + tid * 4));
      short4v s4;
      s4[0] = bf16r(f[0]); s4[1] = bf16r(f[1]);
      s4[2] = bf16r(f[2]); s4[3] = bf16r(f[3]);
      *(short4v*)(dst + u * 1024 + tid * 4) = s4;
    }
  }
}

// ===== main: in-block int4+ballot mask pack + swapped-QK^T + reg softmax ====
__global__ __launch_bounds__(256, 4)
void sdpa_fused(const short* __restrict__ Kbf, const short* __restrict__ Vt,
                const short* __restrict__ Qbf, const int* __restrict__ KM,
                const int* __restrict__ QM,
                float* __restrict__ OUT, float* __restrict__ ATT)
{
  __shared__ short sc[TQ * SSTR];        // bf16 attn overlay
  __shared__ float cmb[2][64];           // cross-wave max / sum partials
  __shared__ unsigned pk[2][16][17];     // packed masks [mask][row][wv*4+quad], +1 pad

  const int bid  = blockIdx.x;
  const int wg   = ((bid & 7) << 9) | (bid >> 3);   // XCD-contiguous, bijective
  const int b    = wg >> 5;
  const int q0   = (wg & 31) * TQ;
  const int tid  = threadIdx.x;
  const int lane = tid & 63;
  const int wv   = tid >> 6;
  const int lm   = lane & 15;
  const int quad = lane >> 4;

  // ---- mask pack: int4 coalesced loads + ballot, 2-deep pipeline ----------
  // pair p = (m, r): row rr = wv*4+r of mask m. Lane loads keys
  // [4*lane..4*lane+3] (c0, keys 0..255) and [256+4*lane..] (c1, 256..511).
  // Ballot B[e] has key 4l+e at bit l. Consumer dword (wvv,qd):
  //   bit t*4+e = B[e] bit ((wvv&1)*32 + qd + 4t), B from c0 if wvv<2 else c1.
  // Spot-verified at keys 37, 300, 500.
  {
    int4v c0, c1, n0, n1;
    {
      const int* s0 = KM + ((size_t)(b * LQ + q0 + wv * 4)) * LK + lane * 4;
      c0 = __builtin_nontemporal_load((const int4v*)(s0));
      c1 = __builtin_nontemporal_load((const int4v*)(s0 + 256));
    }
#pragma unroll
    for (int p = 0; p < 8; ++p) {
      const int m = p >> 2, r = p & 3;
      if (p < 7) {
        const int mn = (p + 1) >> 2, rn = (p + 1) & 3;
        const int* sn = (mn ? QM : KM) +
                        ((size_t)(b * LQ + q0 + wv * 4 + rn)) * LK + lane * 4;
        n0 = __builtin_nontemporal_load((const int4v*)(sn));
        n1 = __builtin_nontemporal_load((const int4v*)(sn + 256));
      }
      unsigned long long B0[4], B1[4];
#pragma unroll
      for (int e = 0; e < 4; ++e) {
        B0[e] = __ballot(c0[e] != 0);
        B1[e] = __ballot(c1[e] != 0);
      }
      if (lane < 16) {
        const int wvv = lane >> 2, qd = lane & 3;
        const int sh  = ((wvv & 1) << 5) + qd;
        unsigned d = 0;
#pragma unroll
        for (int e = 0; e < 4; ++e) {
          unsigned long long Be = (wvv < 2) ? B0[e] : B1[e];
          d |= ((unsigned)(Be >> sh) & 0x11111111u) << e;
        }
        pk[m][wv * 4 + r][lane] = d;
      }
      c0 = n0; c1 = n1;
    }
  }

  const size_t qg    = (size_t)(b * LQ + q0 + lm);
  const size_t mbase = qg * LK + wv * 128 + quad * 4;

  // Q B-fragments: two 16B bf16 loads (prepped)
  const short* qp = Qbf + qg * DH + quad * 8;
  const short8v qb0 = *(const short8v*)(qp);
  const short8v qb1 = *(const short8v*)(qp + 32);

  // ---------------- phase 1: S^T tiles, scores stay in registers ----------
  float s[32];
  const short* kp0 = Kbf + ((size_t)(b * LK + wv * 128 + lm)) * DH + quad * 8;
#pragma unroll
  for (int t = 0; t < 8; ++t) {
    const short* kp = kp0 + (size_t)t * 16 * DH;
    short8v ka0 = *(const short8v*)(kp);
    short8v ka1 = *(const short8v*)(kp + 32);
    float4v acc = {0.f, 0.f, 0.f, 0.f};
    acc = __builtin_amdgcn_mfma_f32_16x16x32_bf16(ka0, qb0, acc, 0, 0, 0);
    acc = __builtin_amdgcn_mfma_f32_16x16x32_bf16(ka1, qb1, acc, 0, 0, 0);
#pragma unroll
    for (int j = 0; j < 4; ++j) s[t * 4 + j] = acc[j];
  }

  __syncthreads();   // pk visible to all waves
  const unsigned kb  = pk[0][lm][wv * 4 + quad];
  const unsigned qmb = pk[1][lm][wv * 4 + quad];

  // ---------------- phase 2: masks + softmax (in-register) ----------------
  float mx0 = -INFINITY, mx1 = -INFINITY, mx2 = -INFINITY, mx3 = -INFINITY;
#pragma unroll
  for (int t = 0; t < 8; ++t) {
#pragma unroll
    for (int e = 0; e < 4; ++e) {
      float v = ((kb >> (t * 4 + e)) & 1u) ? -INFINITY : s[t * 4 + e];
      s[t * 4 + e] = v;
      if (e == 0) mx0 = fmaxf(mx0, v);
      else if (e == 1) mx1 = fmaxf(mx1, v);
      else if (e == 2) mx2 = fmaxf(mx2, v);
      else mx3 = fmaxf(mx3, v);
    }
  }
  float mx = fmaxf(fmaxf(mx0, mx1), fmaxf(mx2, mx3));
  mx = fmaxf(mx, __shfl_xor(mx, 16, 64));
  mx = fmaxf(mx, __shfl_xor(mx, 32, 64));
  if (lane < 16) cmb[0][wv * 16 + lane] = mx;
  __syncthreads();
  mx = fmaxf(fmaxf(cmb[0][lm], cmb[0][16 + lm]),
             fmaxf(cmb[0][32 + lm], cmb[0][48 + lm]));

  float s0 = 0.f, s1 = 0.f, s2 = 0.f, s3 = 0.f;
#pragma unroll
  for (int t = 0; t < 8; ++t) {
    float p0 = __expf((s[t * 4 + 0] - mx) * 0.125f);
    float p1 = __expf((s[t * 4 + 1] - mx) * 0.125f);
    float p2 = __expf((s[t * 4 + 2] - mx) * 0.125f);
    float p3 = __expf((s[t * 4 + 3] - mx) * 0.125f);
    s[t * 4 + 0] = p0; s[t * 4 + 1] = p1;
    s[t * 4 + 2] = p2; s[t * 4 + 3] = p3;
    s0 += p0; s1 += p1; s2 += p2; s3 += p3;
  }
  float sum = (s0 + s1) + (s2 + s3);
  sum += __shfl_xor(sum, 16, 64);
  sum += __shfl_xor(sum, 32, 64);
  if (lane < 16) cmb[1][wv * 16 + lane] = sum;
  __syncthreads();
  sum = (cmb[1][lm] + cmb[1][16 + lm]) + (cmb[1][32 + lm] + cmb[1][48 + lm]);
  const float inv = __builtin_amdgcn_rcpf(sum);

  // ATT store (plain: L2 merges 64B halves into full lines) + bf16 overlay
  float* arow = ATT + mbase;
  short* srow = &sc[lm * SSTR + wv * 128 + quad * 4];
#pragma unroll
  for (int t = 0; t < 8; ++t) {
    float4v a4;
#pragma unroll
    for (int e = 0; e < 4; ++e)
      a4[e] = ((qmb >> (t * 4 + e)) & 1u) ? 0.f : s[t * 4 + e] * inv;
    *(float4v*)(arow + t * 16) = a4;
    short4v ab;
    ab[0] = bf16r(a4[0]); ab[1] = bf16r(a4[1]);
    ab[2] = bf16r(a4[2]); ab[3] = bf16r(a4[3]);
    *(short4v*)(srow + t * 16) = ab;
  }
  __syncthreads();   // overlay complete before A-frag reads

  // ---------------- phase 3: O = A * Vt (barrier-free) --------------------
  float4v oa = {0.f, 0.f, 0.f, 0.f}, ob = {0.f, 0.f, 0.f, 0.f};
  const short* ap = &sc[lm * SSTR + quad * 8];
  const short* vp = Vt + ((size_t)(b * DH + wv * 16 + lm)) * LK + quad * 8;
#pragma unroll
  for (int c = 0; c < 16; c += 2) {
    short8v a0 = *(const short8v*)(ap + c * 32);
    short8v b0 = *(const short8v*)(vp + c * 32);
    short8v a1 = *(const short8v*)(ap + (c + 1) * 32);
    short8v b1 = *(const short8v*)(vp + (c + 1) * 32);
    oa = __builtin_amdgcn_mfma_f32_16x16x32_bf16(a0, b0, oa, 0, 0, 0);
    ob = __builtin_amdgcn_mfma_f32_16x16x32_bf16(a1, b1, ob, 0, 0, 0);
  }
  float4v oacc = oa + ob;
  float* obase = OUT + ((size_t)(b * LQ + q0 + quad * 4)) * DH + wv * 16 + lm;
  obase[0 * DH] = oacc[0];
  obase[1 * DH] = oacc[1];
  obase[2 * DH] = oacc[2];
  obase[3 * DH] = oacc[3];
}

// ======================= fallback (no workspace) ============================
__global__ __launch_bounds__(256, 4)
void sdpa_fallback(const float* __restrict__ Q, const float* __restrict__ K,
                   const float* __restrict__ V, const int* __restrict__ KM,
                   const int* __restrict__ QM, float* __restrict__ OUT,
                   float* __restrict__ ATT)
{
  __shared__ short kvs[64 * VROW];
  __shared__ short scs[TQ * SSTR];
  const int bid  = blockIdx.x;
  const int wg   = ((bid & 7) << 9) | (bid >> 3);
  const int b    = wg >> 5;
  const int q0   = (wg & 31) * TQ;
  const int tid  = threadIdx.x;
  const int lane = tid & 63;
  const int wave = tid >> 6;
  const int lm   = lane & 15;
  const int quad = lane >> 4;
  const int row  = tid >> 4;
  const int col  = tid & 15;
  const size_t gro = (size_t)(b * LQ + q0 + row) * LK;
  int4v km8[8];
#pragma unroll
  for (int j = 0; j < 8; ++j)
    km8[j] = *(const int4v*)(KM + gro + col * 4 + j * 64);
  const float* qrow = Q + ((size_t)(b * LQ + q0 + lm)) * DH + quad * 8;
  short8v aq0, aq1;
  {
    float4v f0 = *(const float4v*)(qrow + 0);
    float4v f1 = *(const float4v*)(qrow + 4);
    float4v f2 = *(const float4v*)(qrow + 32);
    float4v f3 = *(const float4v*)(qrow + 36);
#pragma unroll
    for (int e = 0; e < 4; ++e) {
      aq0[e] = bf16r(f0[e]); aq0[e + 4] = bf16r(f1[e]);
      aq1[e] = bf16r(f2[e]); aq1[e + 4] = bf16r(f3[e]);
    }
  }
  unsigned kbm = 0;
#pragma unroll
  for (int j = 0; j < 8; ++j)
#pragma unroll
    for (int e = 0; e < 4; ++e) kbm |= (unsigned)(km8[j][e] != 0) << (j * 4 + e);
  const float* kbp = K + ((size_t)(b * LK + lm)) * DH + quad * 8;
#pragma unroll
  for (int t = 0; t < 8; ++t) {
    const float* kr = kbp + (size_t)(wave * 8 + t) * 16 * DH;
    float4v f0 = *(const float4v*)(kr + 0);
    float4v f1 = *(const float4v*)(kr + 4);
    float4v f2 = *(const float4v*)(kr + 32);
    float4v f3 = *(const float4v*)(kr + 36);
    short8v b0, b1;
#pragma unroll
    for (int e = 0; e < 4; ++e) {
      b0[e] = bf16r(f0[e]); b0[e + 4] = bf16r(f1[e]);
      b1[e] = bf16r(f2[e]); b1[e + 4] = bf16r(f3[e]);
    }
    float4v acc = {0.f, 0.f, 0.f, 0.f};
    acc = __builtin_amdgcn_mfma_f32_16x16x32_bf16(aq0, b0, acc, 0, 0, 0);
    acc = __builtin_amdgcn_mfma_f32_16x16x32_bf16(aq1, b1, acc, 0, 0, 0);
    const int n = (wave * 8 + t) * 16 + lm;
#pragma unroll
    for (int j = 0; j < 4; ++j)
      *(_Float16*)&scs[(quad * 4 + j) * SSTR + n] = (_Float16)acc[j];
  }
  int4v qm8[8];
#pragma unroll
  for (int j = 0; j < 8; ++j)
    qm8[j] = *(const int4v*)(QM + gro + col * 4 + j * 64);
  __syncthreads();
  float s[32];
  float mx = -INFINITY;
#pragma unroll
  for (int j = 0; j < 8; ++j) {
    half4v h4 = *(const half4v*)&scs[row * SSTR + col * 4 + j * 64];
#pragma unroll
    for (int e = 0; e < 4; ++e) {
      float val = ((kbm >> (j * 4 + e)) & 1u) ? -INFINITY : (float)h4[e];
      s[j * 4 + e] = val;
      mx = fmaxf(mx, val);
    }
  }
#pragma unroll
  for (int off = 8; off; off >>= 1) mx = fmaxf(mx, __shfl_xor(mx, off, 64));
  unsigned qbm = 0;
#pragma unroll
  for (int j = 0; j < 8; ++j)
#pragma unroll
    for (int e = 0; e < 4; ++e) qbm |= (unsigned)(qm8[j][e] != 0) << (j * 4 + e);
  float sum = 0.f;
#pragma unroll
  for (int j = 0; j < 32; ++j) {
    float p = __expf((s[j] - mx) * 0.125f);
    s[j] = p; sum += p;
  }
#pragma unroll
  for (int off = 8; off; off >>= 1) sum += __shfl_xor(sum, off, 64);
  const float inv = 1.f / sum;
  float* arow = ATT + gro;
#pragma unroll
  for (int j = 0; j < 8; ++j) {
    int kk = col * 4 + j * 64;
    float4v a4;
#pragma unroll
    for (int e = 0; e < 4; ++e)
      a4[e] = ((qbm >> (j * 4 + e)) & 1u) ? 0.f : s[j * 4 + e] * inv;
    *(float4v*)(arow + kk) = a4;
    short4v ab;
    ab[0] = bf16r(a4[0]); ab[1] = bf16r(a4[1]);
    ab[2] = bf16r(a4[2]); ab[3] = bf16r(a4[3]);
    *(short4v*)&scs[row * SSTR + kk] = ab;
  }
  float4v oacc = {0.f, 0.f, 0.f, 0.f};
  const float* vbase = V + ((size_t)b * LK) * DH;
#pragma unroll
  for (int kt = 0; kt < 8; ++kt) {
    const float* vp = vbase + (kt * 64 + row * 4) * DH + col * 4;
    float4v r0 = *(const float4v*)(vp);
    float4v r1 = *(const float4v*)(vp + DH);
    float4v r2 = *(const float4v*)(vp + 2 * DH);
    float4v r3 = *(const float4v*)(vp + 3 * DH);
#pragma unroll
    for (int e = 0; e < 4; ++e) {
      int d = col * 4 + e;
      int gp = row ^ (d & 15);
      short4v s4;
      s4[0] = bf16r(r0[e]); s4[1] = bf16r(r1[e]);
      s4[2] = bf16r(r2[e]); s4[3] = bf16r(r3[e]);
      *(short4v*)&kvs[d * VROW + gp * 4] = s4;
    }
    __syncthreads();
#pragma unroll
    for (int ks = 0; ks < 2; ++ks) {
      const short* ap = &scs[lm * SSTR + kt * 64 + ks * 32 + quad * 8];
      short8v a8 = *(const short8v*)ap;
      int n  = wave * 16 + lm;
      int g0 = ks * 8 + quad * 2;
      short4v lo = *(const short4v*)&kvs[n * VROW + ((g0) ^ (n & 15)) * 4];
      short4v hi = *(const short4v*)&kvs[n * VROW + ((g0 + 1) ^ (n & 15)) * 4];
      short8v b8;
      b8[0] = lo[0]; b8[1] = lo[1]; b8[2] = lo[2]; b8[3] = lo[3];
      b8[4] = hi[0]; b8[5] = hi[1]; b8[6] = hi[2]; b8[7] = hi[3];
      oacc = __builtin_amdgcn_mfma_f32_16x16x32_bf16(a8, b8, oacc, 0, 0, 0);
    }
    __syncthreads();
  }
  float* obase = OUT + ((size_t)(b * LQ + q0 + quad * 4)) * DH + wave * 16 + lm;
  obase[0 * DH] = oacc[0];
  obase[1 * DH] = oacc[1];
  obase[2 * DH] = oacc[2];
  obase[3 * DH] = oacc[3];
}

extern "C" void kernel_launch(void* const* d_in, const int* in_sizes, int n_in,
                              void* d_out, int out_size, void* d_ws, size_t ws_size,
                              hipStream_t stream) {
  const float* q  = (const float*)d_in[0];
  const float* k  = (const float*)d_in[1];
  const float* v  = (const float*)d_in[2];
  const int*   km = (const int*)d_in[3];
  const int*   qm = (const int*)d_in[4];
  float* out  = (float*)d_out;
  float* attn = out + (size_t)BATCH * LQ * DH;
  if (d_ws != nullptr && ws_size >= WS_BYTES_QKV) {
    short* ws = (short*)d_ws;
    hipLaunchKernelGGL(prep_kernel, dim3(1280), dim3(256), 0, stream,
                       q, k, v, ws);
    hipLaunchKernelGGL(sdpa_fused, dim3(BATCH * (LQ / TQ)), dim3(256), 0,
                       stream, ws + WS_K, ws + WS_V, ws + WS_Q, km, qm,
                       out, attn);
  } else {
    hipLaunchKernelGGL(sdpa_fallback, dim3(BATCH * (LQ / TQ)), dim3(256), 0,
                       stream, q, k, v, km, qm, out, attn);
  }
}